// Round 6
// baseline (32.147 us; speedup 1.0000x reference)
//
#include <hip/hip_runtime.h>

// LRT loss: ce  = -(log_softmax(outputs) * targets).sum()/B
//           lrt = -((A[index] @ soft_labels[index]) * log_softmax(outputs)).sum()/B
// out = ce + (epoch >= 10 ? lrt : 0)
// B=8192, C=64, A is [N,64,64] f32. Memory-bound: 134 MB gathered A rows.
//
// Single compute kernel: 256 blocks x 1024 thr (16 waves = 1 block/CU).
// One wave = one sample per iteration (2 iterations). Coalesced A reads:
// chunk k, lane l loads float4 at flat idx k*64+l -> contiguous 1 KB/instr.
// sum_r v_r*ls_r == sum_lanes p_lane * ls[row(lane)] -> no group reduction.
// Final reduce: LDS across 16 waves -> ONE atomicAdd per block (256 total;
// R3 showed 2048 same-addr atomics cost ~5-10us, 256 is sub-us).
// d_out zeroed by 4-byte memsetAsync node (graph-safe).

#define CDIM 64
#define NBLOCKS 256

__global__ __launch_bounds__(1024, 4) void lrt_fused(
    const float* __restrict__ outputs,
    const float* __restrict__ targets,
    const float* __restrict__ A,
    const float* __restrict__ soft_labels,
    const int* __restrict__ epoch,
    const int* __restrict__ index,
    float* __restrict__ out,
    int B)
{
    const int w = threadIdx.x >> 6;   // wave in block (0..15)
    const int l = threadIdx.x & 63;   // lane
    const int wave0 = blockIdx.x * 16 + w;
    const int nwaves = gridDim.x * 16;
    const float gate = (epoch[0] >= 10) ? 1.0f : 0.0f;

    float val = 0.0f;   // accumulates over this wave's samples

    for (int b = wave0; b < B; b += nwaves) {
        // idx is wave-uniform: force scalar so A-loads get an SGPR base
        const int idx = __builtin_amdgcn_readfirstlane(index[b]);

        // Issue all 16 coalesced 1KB loads up front
        const float4* __restrict__ A4 =
            reinterpret_cast<const float4*>(A + (size_t)idx * (CDIM * CDIM));
        float4 a0, a1, a2, a3, a4, a5, a6, a7, a8, a9, a10, a11, a12, a13, a14, a15;
        a0  = A4[ 0 * 64 + l];  a1  = A4[ 1 * 64 + l];
        a2  = A4[ 2 * 64 + l];  a3  = A4[ 3 * 64 + l];
        a4  = A4[ 4 * 64 + l];  a5  = A4[ 5 * 64 + l];
        a6  = A4[ 6 * 64 + l];  a7  = A4[ 7 * 64 + l];
        a8  = A4[ 8 * 64 + l];  a9  = A4[ 9 * 64 + l];
        a10 = A4[10 * 64 + l];  a11 = A4[11 * 64 + l];
        a12 = A4[12 * 64 + l];  a13 = A4[13 * 64 + l];
        a14 = A4[14 * 64 + l];  a15 = A4[15 * 64 + l];

        const float x  = outputs[(size_t)b * CDIM + l];
        const float tg = targets[(size_t)b * CDIM + l];
        const float sv = soft_labels[(size_t)idx * CDIM + l];

        // wave softmax (lane = class) — overlaps with A loads in flight
        float m = x;
        #pragma unroll
        for (int o = 32; o >= 1; o >>= 1) m = fmaxf(m, __shfl_xor(m, o));
        float e = expf(x - m);
        float s = e;
        #pragma unroll
        for (int o = 32; o >= 1; o >>= 1) s += __shfl_xor(s, o);
        const float ls = x - m - logf(s);   // log_softmax[b][l]

        // broadcast the 4 soft-label values this lane needs
        const int c0 = (l & 15) * 4;
        const float sb0 = __shfl(sv, c0 + 0);
        const float sb1 = __shfl(sv, c0 + 1);
        const float sb2 = __shfl(sv, c0 + 2);
        const float sb3 = __shfl(sv, c0 + 3);
        const int rbase = l >> 4;           // row offset within chunk's 4 rows

        float acc = 0.0f;
        #define CONSUME(k, av)                                            \
        {                                                                 \
            float p = av.x * sb0;                                         \
            p = fmaf(av.y, sb1, p);                                       \
            p = fmaf(av.z, sb2, p);                                       \
            p = fmaf(av.w, sb3, p);                                       \
            acc = fmaf(p, __shfl(ls, k * 4 + rbase), acc);                \
        }
        CONSUME(0, a0)   CONSUME(1, a1)   CONSUME(2, a2)   CONSUME(3, a3)
        CONSUME(4, a4)   CONSUME(5, a5)   CONSUME(6, a6)   CONSUME(7, a7)
        CONSUME(8, a8)   CONSUME(9, a9)   CONSUME(10, a10) CONSUME(11, a11)
        CONSUME(12, a12) CONSUME(13, a13) CONSUME(14, a14) CONSUME(15, a15)
        #undef CONSUME

        val += -ls * tg - gate * acc;
    }

    // wave reduce
    #pragma unroll
    for (int o = 32; o >= 1; o >>= 1) val += __shfl_xor(val, o);

    // block reduce across 16 waves -> one atomic per block
    __shared__ float red[16];
    if (l == 0) red[w] = val;
    __syncthreads();
    if (threadIdx.x < 64) {
        float v = (l < 16) ? red[l] : 0.0f;
        #pragma unroll
        for (int o = 8; o >= 1; o >>= 1) v += __shfl_xor(v, o);
        if (l == 0) atomicAdd(out, v * (1.0f / 8192.0f));
    }
}

extern "C" void kernel_launch(void* const* d_in, const int* in_sizes, int n_in,
                              void* d_out, int out_size, void* d_ws, size_t ws_size,
                              hipStream_t stream) {
    const float* outputs     = (const float*)d_in[0];
    const float* targets     = (const float*)d_in[1];
    const float* A           = (const float*)d_in[2];
    const float* soft_labels = (const float*)d_in[3];
    const int*   epoch       = (const int*)d_in[4];
    const int*   index       = (const int*)d_in[5];

    const int B = in_sizes[5];          // 8192 samples

    hipMemsetAsync(d_out, 0, sizeof(float), stream);
    lrt_fused<<<NBLOCKS, 1024, 0, stream>>>(outputs, targets, A, soft_labels,
                                            epoch, index, (float*)d_out, B);
}

// Round 8
// 26.795 us; speedup vs baseline: 1.1997x; 1.1997x over previous
//
#include <hip/hip_runtime.h>

// LRT loss: ce  = -(log_softmax(outputs) * targets).sum()/B
//           lrt = -((A[index] @ soft_labels[index]) * log_softmax(outputs)).sum()/B
// out = ce + (epoch >= 10 ? lrt : 0)
// B=8192, C=64, A is [N,64,64] f32. Memory-bound: 134 MB gathered A rows.
//
// R5 structure (best: 28.95us): 1024 blocks x 256 thr, wave = sample,
// grid-stride 2 samples/wave, two-stage reduce (no atomics, no memset).
// R8 = R7 with the compile fix: __builtin_nontemporal_load needs a NATIVE
// vector type (ext_vector_type), not HIP_vector_type<float,4>.
// Software-pipelined scalars: next iteration's index/outputs/targets/
// soft_labels prefetched while current A-loads are in flight.

#define CDIM 64
#define NBLOCKS 1024

typedef float floatx4 __attribute__((ext_vector_type(4)));

__global__ __launch_bounds__(256, 4) void lrt_stage1(
    const float* __restrict__ outputs,
    const float* __restrict__ targets,
    const float* __restrict__ A,
    const float* __restrict__ soft_labels,
    const int* __restrict__ epoch,
    const int* __restrict__ index,
    float* __restrict__ partial,
    int B)
{
    const int w = threadIdx.x >> 6;   // wave in block (0..3)
    const int l = threadIdx.x & 63;   // lane
    const int wave0 = blockIdx.x * 4 + w;
    const int nwaves = gridDim.x * 4;
    const float gate = (epoch[0] >= 10) ? 1.0f : 0.0f;

    float val = 0.0f;

    // Prologue: load first sample's scalars
    int b = wave0;
    int   idx = 0;
    float x = 0.0f, tg = 0.0f, sv = 0.0f;
    if (b < B) {
        idx = __builtin_amdgcn_readfirstlane(index[b]);
        x   = outputs[(size_t)b * CDIM + l];
        tg  = targets[(size_t)b * CDIM + l];
        sv  = soft_labels[(size_t)idx * CDIM + l];
    }

    for (; b < B; b += nwaves) {
        // Issue all 16 coalesced 1KB A-loads immediately (idx already in SGPR).
        // Non-temporal: each A row is read exactly once.
        const floatx4* __restrict__ A4 =
            reinterpret_cast<const floatx4*>(A + (size_t)idx * (CDIM * CDIM));
        floatx4 a0, a1, a2, a3, a4, a5, a6, a7, a8, a9, a10, a11, a12, a13, a14, a15;
        a0  = __builtin_nontemporal_load(&A4[ 0 * 64 + l]);
        a1  = __builtin_nontemporal_load(&A4[ 1 * 64 + l]);
        a2  = __builtin_nontemporal_load(&A4[ 2 * 64 + l]);
        a3  = __builtin_nontemporal_load(&A4[ 3 * 64 + l]);
        a4  = __builtin_nontemporal_load(&A4[ 4 * 64 + l]);
        a5  = __builtin_nontemporal_load(&A4[ 5 * 64 + l]);
        a6  = __builtin_nontemporal_load(&A4[ 6 * 64 + l]);
        a7  = __builtin_nontemporal_load(&A4[ 7 * 64 + l]);
        a8  = __builtin_nontemporal_load(&A4[ 8 * 64 + l]);
        a9  = __builtin_nontemporal_load(&A4[ 9 * 64 + l]);
        a10 = __builtin_nontemporal_load(&A4[10 * 64 + l]);
        a11 = __builtin_nontemporal_load(&A4[11 * 64 + l]);
        a12 = __builtin_nontemporal_load(&A4[12 * 64 + l]);
        a13 = __builtin_nontemporal_load(&A4[13 * 64 + l]);
        a14 = __builtin_nontemporal_load(&A4[14 * 64 + l]);
        a15 = __builtin_nontemporal_load(&A4[15 * 64 + l]);

        // Prefetch NEXT sample's scalars while A-loads are in flight
        const int nb = b + nwaves;
        int   nidx = 0;
        float nx = 0.0f, ntg = 0.0f, nsv = 0.0f;
        if (nb < B) {
            nidx = __builtin_amdgcn_readfirstlane(index[nb]);
            nx   = outputs[(size_t)nb * CDIM + l];
            ntg  = targets[(size_t)nb * CDIM + l];
            nsv  = soft_labels[(size_t)nidx * CDIM + l];
        }

        // wave softmax (lane = class) — overlaps with A loads in flight
        float m = x;
        #pragma unroll
        for (int o = 32; o >= 1; o >>= 1) m = fmaxf(m, __shfl_xor(m, o));
        float e = expf(x - m);
        float s = e;
        #pragma unroll
        for (int o = 32; o >= 1; o >>= 1) s += __shfl_xor(s, o);
        const float ls = x - m - logf(s);   // log_softmax[b][l]

        // broadcast the 4 soft-label values this lane needs
        const int c0 = (l & 15) * 4;
        const float sb0 = __shfl(sv, c0 + 0);
        const float sb1 = __shfl(sv, c0 + 1);
        const float sb2 = __shfl(sv, c0 + 2);
        const float sb3 = __shfl(sv, c0 + 3);
        const int rbase = l >> 4;           // row offset within chunk's 4 rows

        float acc = 0.0f;
        #define CONSUME(k, av)                                            \
        {                                                                 \
            float p = av.x * sb0;                                         \
            p = fmaf(av.y, sb1, p);                                       \
            p = fmaf(av.z, sb2, p);                                       \
            p = fmaf(av.w, sb3, p);                                       \
            acc = fmaf(p, __shfl(ls, k * 4 + rbase), acc);                \
        }
        CONSUME(0, a0)   CONSUME(1, a1)   CONSUME(2, a2)   CONSUME(3, a3)
        CONSUME(4, a4)   CONSUME(5, a5)   CONSUME(6, a6)   CONSUME(7, a7)
        CONSUME(8, a8)   CONSUME(9, a9)   CONSUME(10, a10) CONSUME(11, a11)
        CONSUME(12, a12) CONSUME(13, a13) CONSUME(14, a14) CONSUME(15, a15)
        #undef CONSUME

        val += -ls * tg - gate * acc;

        idx = nidx; x = nx; tg = ntg; sv = nsv;   // rotate pipeline regs
    }

    // wave reduce
    #pragma unroll
    for (int o = 32; o >= 1; o >>= 1) val += __shfl_xor(val, o);

    __shared__ float red[4];
    if (l == 0) red[w] = val;
    __syncthreads();
    if (threadIdx.x == 0)
        partial[blockIdx.x] = red[0] + red[1] + red[2] + red[3];
}

__global__ __launch_bounds__(256) void lrt_stage2(
    const float* __restrict__ partial, float* __restrict__ out, int B)
{
    const int t = threadIdx.x;
    // NBLOCKS=1024 partials = 256 float4, one vector load per thread
    const float4 p = reinterpret_cast<const float4*>(partial)[t];
    double acc = (double)p.x + (double)p.y + (double)p.z + (double)p.w;
    #pragma unroll
    for (int o = 32; o >= 1; o >>= 1) acc += __shfl_xor(acc, o);
    __shared__ double red[4];
    if ((t & 63) == 0) red[t >> 6] = acc;
    __syncthreads();
    if (t == 0) out[0] = (float)((red[0] + red[1] + red[2] + red[3]) / (double)B);
}

extern "C" void kernel_launch(void* const* d_in, const int* in_sizes, int n_in,
                              void* d_out, int out_size, void* d_ws, size_t ws_size,
                              hipStream_t stream) {
    const float* outputs     = (const float*)d_in[0];
    const float* targets     = (const float*)d_in[1];
    const float* A           = (const float*)d_in[2];
    const float* soft_labels = (const float*)d_in[3];
    const int*   epoch       = (const int*)d_in[4];
    const int*   index       = (const int*)d_in[5];

    const int B = in_sizes[5];          // 8192 samples
    float* partial = (float*)d_ws;      // NBLOCKS floats, overwritten each call

    lrt_stage1<<<NBLOCKS, 256, 0, stream>>>(outputs, targets, A, soft_labels,
                                            epoch, index, partial, B);
    lrt_stage2<<<1, 256, 0, stream>>>(partial, (float*)d_out, B);
}